// Round 3
// baseline (283.252 us; speedup 1.0000x reference)
//
#include <hip/hip_runtime.h>
#include <cstdint>
#include <cstddef>

// T=1024 tokens, H=2048, F=1024, E=8, K=2
#define T_TOK 1024
#define H_DIM 2048
#define F_DIM 1024
#define E_EXP 8
#define BM 64
#define BN 64
#define BK 64
#define SP 70          // LDS row stride in bf16 (140 B: bank step 3, coprime 32)
#define MAX_TILES 40
#define ROWCAP 2560

// ---- workspace layout ----
#define I_NTILES 25     // int
#define I_TILE_E 32     // int[48]
#define I_TILE_R0 80    // int[48]
#define I_ROWTOK 4224   // int[2560]
#define I_ROWW   6784   // float[2560]
#define B_XB     37888                       // bf16 x [1024][2048]
#define B_AWS    (37888 + T_TOK*H_DIM*2)     // bf16 act [2560][1024]

typedef __bf16 bf16x8 __attribute__((ext_vector_type(8)));
typedef __bf16 bf16x4 __attribute__((ext_vector_type(4)));
typedef float  f32x4  __attribute__((ext_vector_type(4)));

#define MFMA(a,b,c) __builtin_amdgcn_mfma_f32_16x16x32_bf16(a,b,c,0,0,0)

// ---------------- fused router + scan + assign (1 block, 1024 thr) ----------------
__global__ __launch_bounds__(1024) void k_route(const float* __restrict__ logits,
                                                int* __restrict__ ws_i) {
  __shared__ int cnt[E_EXP], cur[E_EXP], offs_s[E_EXP];
  const int t = threadIdx.x;
  float* ws_f = (float*)ws_i;
  if (t < E_EXP) { cnt[t] = 0; cur[t] = 0; }
  __syncthreads();
  float l[E_EXP];
#pragma unroll
  for (int e = 0; e < E_EXP; ++e) l[e] = logits[t * E_EXP + e];
  int b0 = 0; float v0 = l[0];
#pragma unroll
  for (int e = 1; e < E_EXP; ++e) if (l[e] > v0) { v0 = l[e]; b0 = e; }
  int b1 = -1; float v1 = -3.4e38f;
#pragma unroll
  for (int e = 0; e < E_EXP; ++e) if (e != b0 && l[e] > v1) { v1 = l[e]; b1 = e; }
  float w0 = 1.f / (1.f + __expf(v1 - v0));
  float w1 = 1.f - w0;
  atomicAdd(&cnt[b0], 1);
  atomicAdd(&cnt[b1], 1);
  __syncthreads();
  if (t == 0) {
    int off = 0, nt = 0;
    for (int e = 0; e < E_EXP; ++e) {
      offs_s[e] = off;
      int ntile = (cnt[e] + BM - 1) / BM;
      for (int i = 0; i < ntile; ++i) {
        ws_i[I_TILE_E + nt] = e;
        ws_i[I_TILE_R0 + nt] = off + i * BM;
        ++nt;
      }
      off += ntile * BM;
    }
    ws_i[I_NTILES] = nt;
  }
  for (int i = t; i < ROWCAP; i += 1024) ws_i[I_ROWTOK + i] = -1;
  __syncthreads();
  {
    int p = atomicAdd(&cur[b0], 1);
    int s = offs_s[b0] + p;
    ws_i[I_ROWTOK + s] = t;
    ws_f[I_ROWW + s] = w0;
  }
  {
    int p = atomicAdd(&cur[b1], 1);
    int s = offs_s[b1] + p;
    ws_i[I_ROWTOK + s] = t;
    ws_f[I_ROWW + s] = w1;
  }
}

// ---------------- x fp32 -> bf16 ----------------
__global__ __launch_bounds__(256) void k_cvt(const float* __restrict__ x,
                                             __bf16* __restrict__ xb) {
  long i = (long)(blockIdx.x * 256 + threadIdx.x) * 8;
  float4 a = *(const float4*)(x + i);
  float4 b = *(const float4*)(x + i + 4);
  bf16x8 v;
  v[0] = (__bf16)a.x; v[1] = (__bf16)a.y; v[2] = (__bf16)a.z; v[3] = (__bf16)a.w;
  v[4] = (__bf16)b.x; v[5] = (__bf16)b.y; v[6] = (__bf16)b.z; v[7] = (__bf16)b.w;
  *(bf16x8*)(xb + i) = v;
}

// staging macros (named sets; 2-deep pipeline, rule #20: static indexing only)
#define LOADG1(S, K0) do { \
  rA0_##S = *(const bf16x8*)(xA0 + (K0)); \
  rA1_##S = *(const bf16x8*)(xA1 + (K0)); \
  _Pragma("unroll") \
  for (int j = 0; j < 4; ++j) { \
    q1_##S[j] = *(const f32x4*)(pB1 + (size_t)((K0) + j) * F_DIM); \
    q3_##S[j] = *(const f32x4*)(pB3 + (size_t)((K0) + j) * F_DIM); \
  } } while (0)

#define WRITEL1(S) do { \
  *(bf16x8*)&As[ar][ac] = rA0_##S; \
  *(bf16x8*)&As[ar + 32][ac] = rA1_##S; \
  _Pragma("unroll") \
  for (int u = 0; u < 4; ++u) { \
    bf16x4 v1, v3; \
    _Pragma("unroll") \
    for (int j = 0; j < 4; ++j) { v1[j] = (__bf16)q1_##S[j][u]; v3[j] = (__bf16)q3_##S[j][u]; } \
    *(bf16x4*)&B1s[nb + u][kq] = v1; \
    *(bf16x4*)&B3s[nb + u][kq] = v3; \
  } } while (0)

// ---------------- GEMM1: a = silu(x·w1) * (x·w3) -> aws bf16 ----------------
__global__ __launch_bounds__(256, 4) void k_gemm1(const __bf16* __restrict__ xb,
                                                  const float* __restrict__ w1,
                                                  const float* __restrict__ w3,
                                                  const int* __restrict__ ws_i,
                                                  __bf16* __restrict__ aws) {
  __shared__ __bf16 As[BM][SP];
  __shared__ __bf16 B1s[BN][SP];
  __shared__ __bf16 B3s[BN][SP];
  __shared__ int s_tok[BM];
  // XCD swizzle: 640 = 8 * 80
  const int p = blockIdx.x;
  const int lg = (p & 7) * 80 + (p >> 3);
  const int tile = lg % MAX_TILES;
  const int n0 = (lg / MAX_TILES) * BN;
  if (tile >= ws_i[I_NTILES]) return;
  const int e  = ws_i[I_TILE_E + tile];
  const int r0 = ws_i[I_TILE_R0 + tile];
  const int tid = threadIdx.x, lane = tid & 63, wid = tid >> 6;
  const int wm = wid >> 1, wn = wid & 1;
  const int l15 = lane & 15, lk8 = (lane >> 4) << 3;
  const int ar = tid >> 3, ac = (tid & 7) * 8;
  const int nb = (tid & 15) * 4, kq = (tid >> 4) * 4;
  if (tid < BM) {
    int tk = ws_i[I_ROWTOK + r0 + tid];
    s_tok[tid] = tk < 0 ? 0 : tk;
  }
  __syncthreads();
  const int tok0 = s_tok[ar], tok1 = s_tok[ar + 32];
  const __bf16* xA0 = xb + (size_t)tok0 * H_DIM + ac;
  const __bf16* xA1 = xb + (size_t)tok1 * H_DIM + ac;
  const float* pB1 = w1 + (size_t)e * H_DIM * F_DIM + n0 + nb + (size_t)kq * F_DIM;
  const float* pB3 = w3 + (size_t)e * H_DIM * F_DIM + n0 + nb + (size_t)kq * F_DIM;

  bf16x8 rA0_0, rA1_0, rA0_1, rA1_1;
  f32x4 q1_0[4], q3_0[4], q1_1[4], q3_1[4];
  f32x4 accg[2][2] = {}; f32x4 accu[2][2] = {};

  auto COMPUTE = [&]() {
#pragma unroll
    for (int kk = 0; kk < 2; ++kk) {
      const int kb = kk * 32 + lk8;
      bf16x8 a0  = *(const bf16x8*)&As[wm * 32 + l15][kb];
      bf16x8 a1  = *(const bf16x8*)&As[wm * 32 + 16 + l15][kb];
      bf16x8 b10 = *(const bf16x8*)&B1s[wn * 32 + l15][kb];
      bf16x8 b11 = *(const bf16x8*)&B1s[wn * 32 + 16 + l15][kb];
      bf16x8 b30 = *(const bf16x8*)&B3s[wn * 32 + l15][kb];
      bf16x8 b31 = *(const bf16x8*)&B3s[wn * 32 + 16 + l15][kb];
      accg[0][0] = MFMA(a0, b10, accg[0][0]);
      accg[0][1] = MFMA(a0, b11, accg[0][1]);
      accg[1][0] = MFMA(a1, b10, accg[1][0]);
      accg[1][1] = MFMA(a1, b11, accg[1][1]);
      accu[0][0] = MFMA(a0, b30, accu[0][0]);
      accu[0][1] = MFMA(a0, b31, accu[0][1]);
      accu[1][0] = MFMA(a1, b30, accu[1][0]);
      accu[1][1] = MFMA(a1, b31, accu[1][1]);
    }
  };

  LOADG1(0, 0);
  LOADG1(1, BK);
  for (int k0 = 0; k0 < H_DIM; k0 += 2 * BK) {
    if (k0) __syncthreads();
    WRITEL1(0);
    if (k0 + 2 * BK < H_DIM) LOADG1(0, k0 + 2 * BK);
    __syncthreads();
    COMPUTE();
    __syncthreads();
    WRITEL1(1);
    if (k0 + 3 * BK < H_DIM) LOADG1(1, k0 + 3 * BK);
    __syncthreads();
    COMPUTE();
  }
  // epilogue: silu(g)*u -> bf16 (C layout: col=lane&15, row=(lane>>4)*4+reg)
#pragma unroll
  for (int fm = 0; fm < 2; ++fm)
#pragma unroll
    for (int fn = 0; fn < 2; ++fn)
#pragma unroll
      for (int r = 0; r < 4; ++r) {
        float g = accg[fm][fn][r], u = accu[fm][fn][r];
        float a = g / (1.f + __expf(-g)) * u;
        int row = r0 + wm * 32 + fm * 16 + ((lane >> 4) << 2) + r;
        int col = n0 + wn * 32 + fn * 16 + l15;
        aws[(size_t)row * F_DIM + col] = (__bf16)a;
      }
}

#define LOADG2(S, K0) do { \
  rA0_##S = *(const bf16x8*)(pA0 + (K0)); \
  rA1_##S = *(const bf16x8*)(pA1 + (K0)); \
  _Pragma("unroll") \
  for (int j = 0; j < 4; ++j) \
    q2_##S[j] = *(const f32x4*)(pB2 + (size_t)((K0) + j) * H_DIM); \
  } while (0)

#define WRITEL2(S) do { \
  *(bf16x8*)&As[ar][ac] = rA0_##S; \
  *(bf16x8*)&As[ar + 32][ac] = rA1_##S; \
  _Pragma("unroll") \
  for (int u = 0; u < 4; ++u) { \
    bf16x4 v; \
    _Pragma("unroll") \
    for (int j = 0; j < 4; ++j) v[j] = (__bf16)q2_##S[j][u]; \
    *(bf16x4*)&Bs[nb + u][kq] = v; \
  } } while (0)

// ---------------- GEMM2: y = a·w2, weighted atomic scatter ----------------
__global__ __launch_bounds__(256, 4) void k_gemm2(const __bf16* __restrict__ aws,
                                                  const float* __restrict__ w2,
                                                  const int* __restrict__ ws_i,
                                                  float* __restrict__ out) {
  __shared__ __bf16 As[BM][SP];
  __shared__ __bf16 Bs[BN][SP];
  __shared__ int s_tok[BM];
  __shared__ float s_w[BM];
  const int p = blockIdx.x;                 // 1280 = 8 * 160
  const int lg = (p & 7) * 160 + (p >> 3);
  const int tile = lg % MAX_TILES;
  const int h0 = (lg / MAX_TILES) * BN;
  if (tile >= ws_i[I_NTILES]) return;
  const int e  = ws_i[I_TILE_E + tile];
  const int r0 = ws_i[I_TILE_R0 + tile];
  const int tid = threadIdx.x, lane = tid & 63, wid = tid >> 6;
  const int wm = wid >> 1, wn = wid & 1;
  const int l15 = lane & 15, lk8 = (lane >> 4) << 3;
  const int ar = tid >> 3, ac = (tid & 7) * 8;
  const int nb = (tid & 15) * 4, kq = (tid >> 4) * 4;
  const float* ws_f = (const float*)ws_i;
  if (tid < BM) {
    s_tok[tid] = ws_i[I_ROWTOK + r0 + tid];
    s_w[tid]   = ws_f[I_ROWW + r0 + tid];
  }
  __syncthreads();
  const __bf16* pA0 = aws + (size_t)(r0 + ar) * F_DIM + ac;
  const __bf16* pA1 = aws + (size_t)(r0 + ar + 32) * F_DIM + ac;
  const float* pB2 = w2 + (size_t)e * F_DIM * H_DIM + h0 + nb + (size_t)kq * H_DIM;

  bf16x8 rA0_0, rA1_0, rA0_1, rA1_1;
  f32x4 q2_0[4], q2_1[4];
  f32x4 acc[2][2] = {};

  auto COMPUTE = [&]() {
#pragma unroll
    for (int kk = 0; kk < 2; ++kk) {
      const int kb = kk * 32 + lk8;
      bf16x8 a0 = *(const bf16x8*)&As[wm * 32 + l15][kb];
      bf16x8 a1 = *(const bf16x8*)&As[wm * 32 + 16 + l15][kb];
      bf16x8 b0 = *(const bf16x8*)&Bs[wn * 32 + l15][kb];
      bf16x8 b1 = *(const bf16x8*)&Bs[wn * 32 + 16 + l15][kb];
      acc[0][0] = MFMA(a0, b0, acc[0][0]);
      acc[0][1] = MFMA(a0, b1, acc[0][1]);
      acc[1][0] = MFMA(a1, b0, acc[1][0]);
      acc[1][1] = MFMA(a1, b1, acc[1][1]);
    }
  };

  LOADG2(0, 0);
  LOADG2(1, BK);
  for (int k0 = 0; k0 < F_DIM; k0 += 2 * BK) {
    if (k0) __syncthreads();
    WRITEL2(0);
    if (k0 + 2 * BK < F_DIM) LOADG2(0, k0 + 2 * BK);
    __syncthreads();
    COMPUTE();
    __syncthreads();
    WRITEL2(1);
    if (k0 + 3 * BK < F_DIM) LOADG2(1, k0 + 3 * BK);
    __syncthreads();
    COMPUTE();
  }
  // exactly 2 atomic adds per output element (K=2): order-independent (a+b exact)
#pragma unroll
  for (int fm = 0; fm < 2; ++fm)
#pragma unroll
    for (int fn = 0; fn < 2; ++fn)
#pragma unroll
      for (int r = 0; r < 4; ++r) {
        int lrow = wm * 32 + fm * 16 + ((lane >> 4) << 2) + r;
        int t = s_tok[lrow];
        if (t >= 0) {
          float v = acc[fm][fn][r] * s_w[lrow];
          atomicAdd(out + (size_t)t * H_DIM + h0 + wn * 32 + fn * 16 + l15, v);
        }
      }
}

extern "C" void kernel_launch(void* const* d_in, const int* in_sizes, int n_in,
                              void* d_out, int out_size, void* d_ws, size_t ws_size,
                              hipStream_t stream) {
  (void)in_sizes; (void)n_in; (void)out_size; (void)ws_size;
  const float* x      = (const float*)d_in[0];
  const float* logits = (const float*)d_in[1];
  const float* w1     = (const float*)d_in[2];
  const float* w3     = (const float*)d_in[3];
  const float* w2     = (const float*)d_in[4];
  float* out = (float*)d_out;
  int* ws_i = (int*)d_ws;
  __bf16* xb  = (__bf16*)((char*)d_ws + B_XB);
  __bf16* aws = (__bf16*)((char*)d_ws + B_AWS);

  hipMemsetAsync(d_out, 0, (size_t)T_TOK * H_DIM * sizeof(float), stream);
  k_cvt<<<dim3(T_TOK * H_DIM / (256 * 8)), 256, 0, stream>>>(x, xb);
  k_route<<<1, 1024, 0, stream>>>(logits, ws_i);
  k_gemm1<<<dim3(MAX_TILES * (F_DIM / BN)), 256, 0, stream>>>(xb, w1, w3, ws_i, aws);
  k_gemm2<<<dim3(MAX_TILES * (H_DIM / BN)), 256, 0, stream>>>(aws, w2, ws_i, out);
}

// Round 4
// 122.482 us; speedup vs baseline: 2.3126x; 2.3126x over previous
//
#include <hip/hip_runtime.h>
#include <cstdint>
#include <cstddef>

// T=1024 tokens, H=2048, F=1024, E=8, K=2
#define T_TOK 1024
#define H_DIM 2048
#define F_DIM 1024
#define E_EXP 8
#define BM 64
#define BK 64
#define BN1 32         // gemm1 N-tile (grid doubled for occupancy)
#define BN2 64         // gemm2 N-tile
#define SP 70          // LDS row stride in bf16 (140 B: bank step 3, coprime 32)
#define MAX_TILES 40
#define ROWCAP 2560

// ---- workspace layout ----
#define I_NTILES 25     // int
#define I_TILE_E 32     // int[48]
#define I_TILE_R0 80    // int[48]
#define I_ROWTOK 4224   // int[2560]
#define I_ROWW   6784   // float[2560]
#define B_XB     37888                       // bf16 x [1024][2048]
#define B_AWS    (37888 + T_TOK*H_DIM*2)     // bf16 act [2560][1024]

typedef __bf16 bf16x8 __attribute__((ext_vector_type(8)));
typedef __bf16 bf16x4 __attribute__((ext_vector_type(4)));
typedef __bf16 bf16x2 __attribute__((ext_vector_type(2)));
typedef float  f32x4  __attribute__((ext_vector_type(4)));

#define MFMA(a,b,c) __builtin_amdgcn_mfma_f32_16x16x32_bf16(a,b,c,0,0,0)

// ---------------- fused router + scan + assign (1 block, 1024 thr) ----------------
__global__ __launch_bounds__(1024) void k_route(const float* __restrict__ logits,
                                                int* __restrict__ ws_i) {
  __shared__ int cnt[E_EXP], cur[E_EXP], offs_s[E_EXP];
  const int t = threadIdx.x;
  float* ws_f = (float*)ws_i;
  if (t < E_EXP) { cnt[t] = 0; cur[t] = 0; }
  __syncthreads();
  float l[E_EXP];
#pragma unroll
  for (int e = 0; e < E_EXP; ++e) l[e] = logits[t * E_EXP + e];
  int b0 = 0; float v0 = l[0];
#pragma unroll
  for (int e = 1; e < E_EXP; ++e) if (l[e] > v0) { v0 = l[e]; b0 = e; }
  int b1 = -1; float v1 = -3.4e38f;
#pragma unroll
  for (int e = 0; e < E_EXP; ++e) if (e != b0 && l[e] > v1) { v1 = l[e]; b1 = e; }
  float w0 = 1.f / (1.f + __expf(v1 - v0));
  float w1 = 1.f - w0;
  atomicAdd(&cnt[b0], 1);
  atomicAdd(&cnt[b1], 1);
  __syncthreads();
  if (t == 0) {
    int off = 0, nt = 0;
    for (int e = 0; e < E_EXP; ++e) {
      offs_s[e] = off;
      int ntile = (cnt[e] + BM - 1) / BM;
      for (int i = 0; i < ntile; ++i) {
        ws_i[I_TILE_E + nt] = e;
        ws_i[I_TILE_R0 + nt] = off + i * BM;
        ++nt;
      }
      off += ntile * BM;
    }
    ws_i[I_NTILES] = nt;
  }
  for (int i = t; i < ROWCAP; i += 1024) ws_i[I_ROWTOK + i] = -1;
  __syncthreads();
  {
    int p = atomicAdd(&cur[b0], 1);
    int s = offs_s[b0] + p;
    ws_i[I_ROWTOK + s] = t;
    ws_f[I_ROWW + s] = w0;
  }
  {
    int p = atomicAdd(&cur[b1], 1);
    int s = offs_s[b1] + p;
    ws_i[I_ROWTOK + s] = t;
    ws_f[I_ROWW + s] = w1;
  }
}

// ---------------- x fp32 -> bf16 ----------------
__global__ __launch_bounds__(256) void k_cvt(const float* __restrict__ x,
                                             __bf16* __restrict__ xb) {
  long i = (long)(blockIdx.x * 256 + threadIdx.x) * 8;
  float4 a = *(const float4*)(x + i);
  float4 b = *(const float4*)(x + i + 4);
  bf16x8 v;
  v[0] = (__bf16)a.x; v[1] = (__bf16)a.y; v[2] = (__bf16)a.z; v[3] = (__bf16)a.w;
  v[4] = (__bf16)b.x; v[5] = (__bf16)b.y; v[6] = (__bf16)b.z; v[7] = (__bf16)b.w;
  *(bf16x8*)(xb + i) = v;
}

// ---------------- GEMM1: a = silu(x·w1) * (x·w3) -> aws bf16 ----------------
// BM=64 x BN1=32, 4 waves each owning 16 rows x 32 cols. 1-deep reg prefetch.
__global__ __launch_bounds__(256) void k_gemm1(const __bf16* __restrict__ xb,
                                               const float* __restrict__ w1,
                                               const float* __restrict__ w3,
                                               const int* __restrict__ ws_i,
                                               __bf16* __restrict__ aws) {
  __shared__ __bf16 As[BM][SP];
  __shared__ __bf16 B1s[BN1][SP];
  __shared__ __bf16 B3s[BN1][SP];
  __shared__ int s_tok[BM];
  // XCD swizzle: 1280 = 8 * 160; per XCD: 4 n0-groups x 40 tiles (disjoint panels)
  const int p = blockIdx.x;
  const int lg = (p & 7) * 160 + (p >> 3);
  const int tile = lg % MAX_TILES;
  const int n0 = (lg / MAX_TILES) * BN1;
  if (tile >= ws_i[I_NTILES]) return;
  const int e  = ws_i[I_TILE_E + tile];
  const int r0 = ws_i[I_TILE_R0 + tile];
  const int tid = threadIdx.x, lane = tid & 63, wid = tid >> 6;
  const int wm = wid;                         // 4 waves over M
  const int l15 = lane & 15, lk8 = (lane >> 4) << 3;
  const int ar = tid >> 3, ac = (tid & 7) * 8;        // A: rows ar, ar+32
  const int nb = (tid & 7) * 4, kq = (tid >> 3) * 2;  // B: 4 cols x 2 k-rows
  if (tid < BM) {
    int tk = ws_i[I_ROWTOK + r0 + tid];
    s_tok[tid] = tk < 0 ? 0 : tk;   // padded rows compute garbage, never used
  }
  __syncthreads();
  const int tok0 = s_tok[ar], tok1 = s_tok[ar + 32];
  const __bf16* xA0 = xb + (size_t)tok0 * H_DIM + ac;
  const __bf16* xA1 = xb + (size_t)tok1 * H_DIM + ac;
  const float* pB1 = w1 + (size_t)e * H_DIM * F_DIM + n0 + nb + (size_t)kq * F_DIM;
  const float* pB3 = w3 + (size_t)e * H_DIM * F_DIM + n0 + nb + (size_t)kq * F_DIM;

  bf16x8 rA0, rA1;
  f32x4 q1[2], q3[2];
  f32x4 accg[2] = {}; f32x4 accu[2] = {};

  auto LOADG = [&](int K0) {
    rA0 = *(const bf16x8*)(xA0 + K0);
    rA1 = *(const bf16x8*)(xA1 + K0);
#pragma unroll
    for (int j = 0; j < 2; ++j) {
      q1[j] = *(const f32x4*)(pB1 + (size_t)(K0 + j) * F_DIM);
      q3[j] = *(const f32x4*)(pB3 + (size_t)(K0 + j) * F_DIM);
    }
  };
  auto WRITEL = [&]() {
    *(bf16x8*)&As[ar][ac] = rA0;
    *(bf16x8*)&As[ar + 32][ac] = rA1;
#pragma unroll
    for (int u = 0; u < 4; ++u) {           // b32 stores, 4B-aligned, ~2-way banks
      bf16x2 v1, v3;
      v1[0] = (__bf16)q1[0][u]; v1[1] = (__bf16)q1[1][u];
      v3[0] = (__bf16)q3[0][u]; v3[1] = (__bf16)q3[1][u];
      *(bf16x2*)&B1s[nb + u][kq] = v1;
      *(bf16x2*)&B3s[nb + u][kq] = v3;
    }
  };

  LOADG(0);
  for (int k0 = 0; k0 < H_DIM; k0 += BK) {
    if (k0) __syncthreads();
    WRITEL();
    if (k0 + BK < H_DIM) LOADG(k0 + BK);   // in flight during MFMA phase
    __syncthreads();
    __builtin_amdgcn_s_setprio(1);
#pragma unroll
    for (int kk = 0; kk < 2; ++kk) {
      const int kb = kk * 32 + lk8;
      bf16x8 a   = *(const bf16x8*)&As[wm * 16 + l15][kb];
      bf16x8 b10 = *(const bf16x8*)&B1s[l15][kb];
      bf16x8 b11 = *(const bf16x8*)&B1s[16 + l15][kb];
      bf16x8 b30 = *(const bf16x8*)&B3s[l15][kb];
      bf16x8 b31 = *(const bf16x8*)&B3s[16 + l15][kb];
      accg[0] = MFMA(a, b10, accg[0]);
      accg[1] = MFMA(a, b11, accg[1]);
      accu[0] = MFMA(a, b30, accu[0]);
      accu[1] = MFMA(a, b31, accu[1]);
    }
    __builtin_amdgcn_s_setprio(0);
  }
  // epilogue: silu(g)*u -> bf16 (C layout: col=lane&15, row=(lane>>4)*4+reg)
#pragma unroll
  for (int fn = 0; fn < 2; ++fn)
#pragma unroll
    for (int r = 0; r < 4; ++r) {
      float g = accg[fn][r], u = accu[fn][r];
      float a = g / (1.f + __expf(-g)) * u;
      int row = r0 + wm * 16 + ((lane >> 4) << 2) + r;
      int col = n0 + fn * 16 + l15;
      aws[(size_t)row * F_DIM + col] = (__bf16)a;
    }
}

// ---------------- GEMM2: y = a·w2, weighted atomic scatter ----------------
__global__ __launch_bounds__(256) void k_gemm2(const __bf16* __restrict__ aws,
                                               const float* __restrict__ w2,
                                               const int* __restrict__ ws_i,
                                               float* __restrict__ out) {
  __shared__ __bf16 As[BM][SP];
  __shared__ __bf16 Bs[BN2][SP];
  __shared__ int s_tok[BM];
  __shared__ float s_w[BM];
  const int p = blockIdx.x;                 // 1280 = 8 * 160
  const int lg = (p & 7) * 160 + (p >> 3);
  const int tile = lg % MAX_TILES;
  const int h0 = (lg / MAX_TILES) * BN2;
  if (tile >= ws_i[I_NTILES]) return;
  const int e  = ws_i[I_TILE_E + tile];
  const int r0 = ws_i[I_TILE_R0 + tile];
  const int tid = threadIdx.x, lane = tid & 63, wid = tid >> 6;
  const int wm = wid >> 1, wn = wid & 1;
  const int l15 = lane & 15, lk8 = (lane >> 4) << 3;
  const int ar = tid >> 3, ac = (tid & 7) * 8;
  const int nb = (tid & 15) * 4, kq = (tid >> 4) * 4;
  const float* ws_f = (const float*)ws_i;
  if (tid < BM) {
    s_tok[tid] = ws_i[I_ROWTOK + r0 + tid];
    s_w[tid]   = ws_f[I_ROWW + r0 + tid];
  }
  __syncthreads();
  const __bf16* pA0 = aws + (size_t)(r0 + ar) * F_DIM + ac;
  const __bf16* pA1 = aws + (size_t)(r0 + ar + 32) * F_DIM + ac;
  const float* pB2 = w2 + (size_t)e * F_DIM * H_DIM + h0 + nb + (size_t)kq * H_DIM;

  bf16x8 rA0, rA1;
  f32x4 q2[4];
  auto LOADG = [&](int K0) {
    rA0 = *(const bf16x8*)(pA0 + K0);
    rA1 = *(const bf16x8*)(pA1 + K0);
#pragma unroll
    for (int j = 0; j < 4; ++j) q2[j] = *(const f32x4*)(pB2 + (size_t)(K0 + j) * H_DIM);
  };
  auto WRITEL = [&]() {
    *(bf16x8*)&As[ar][ac] = rA0;
    *(bf16x8*)&As[ar + 32][ac] = rA1;
#pragma unroll
    for (int u = 0; u < 4; ++u) {
      bf16x2 va, vb;
      va[0] = (__bf16)q2[0][u]; va[1] = (__bf16)q2[1][u];
      vb[0] = (__bf16)q2[2][u]; vb[1] = (__bf16)q2[3][u];
      *(bf16x2*)&Bs[nb + u][kq] = va;
      *(bf16x2*)&Bs[nb + u][kq + 2] = vb;
    }
  };

  f32x4 acc[2][2] = {};
  LOADG(0);
  for (int k0 = 0; k0 < F_DIM; k0 += BK) {
    if (k0) __syncthreads();
    WRITEL();
    if (k0 + BK < F_DIM) LOADG(k0 + BK);
    __syncthreads();
    __builtin_amdgcn_s_setprio(1);
#pragma unroll
    for (int kk = 0; kk < 2; ++kk) {
      const int kb = kk * 32 + lk8;
      bf16x8 a0 = *(const bf16x8*)&As[wm * 32 + l15][kb];
      bf16x8 a1 = *(const bf16x8*)&As[wm * 32 + 16 + l15][kb];
      bf16x8 b0 = *(const bf16x8*)&Bs[wn * 32 + l15][kb];
      bf16x8 b1 = *(const bf16x8*)&Bs[wn * 32 + 16 + l15][kb];
      acc[0][0] = MFMA(a0, b0, acc[0][0]);
      acc[0][1] = MFMA(a0, b1, acc[0][1]);
      acc[1][0] = MFMA(a1, b0, acc[1][0]);
      acc[1][1] = MFMA(a1, b1, acc[1][1]);
    }
    __builtin_amdgcn_s_setprio(0);
  }
  // exactly 2 atomic adds per output element (K=2): order-independent (a+b exact)
#pragma unroll
  for (int fm = 0; fm < 2; ++fm)
#pragma unroll
    for (int fn = 0; fn < 2; ++fn)
#pragma unroll
      for (int r = 0; r < 4; ++r) {
        int lrow = wm * 32 + fm * 16 + ((lane >> 4) << 2) + r;
        int t = s_tok[lrow];
        if (t >= 0) {
          float v = acc[fm][fn][r] * s_w[lrow];
          atomicAdd(out + (size_t)t * H_DIM + h0 + wn * 32 + fn * 16 + l15, v);
        }
      }
}

extern "C" void kernel_launch(void* const* d_in, const int* in_sizes, int n_in,
                              void* d_out, int out_size, void* d_ws, size_t ws_size,
                              hipStream_t stream) {
  (void)in_sizes; (void)n_in; (void)out_size; (void)ws_size;
  const float* x      = (const float*)d_in[0];
  const float* logits = (const float*)d_in[1];
  const float* w1     = (const float*)d_in[2];
  const float* w3     = (const float*)d_in[3];
  const float* w2     = (const float*)d_in[4];
  float* out = (float*)d_out;
  int* ws_i = (int*)d_ws;
  __bf16* xb  = (__bf16*)((char*)d_ws + B_XB);
  __bf16* aws = (__bf16*)((char*)d_ws + B_AWS);

  hipMemsetAsync(d_out, 0, (size_t)T_TOK * H_DIM * sizeof(float), stream);
  k_route<<<1, 1024, 0, stream>>>(logits, ws_i);
  k_cvt<<<dim3(T_TOK * H_DIM / (256 * 8)), 256, 0, stream>>>(x, xb);
  k_gemm1<<<dim3(MAX_TILES * (F_DIM / BN1)), 256, 0, stream>>>(xb, w1, w3, ws_i, aws);
  k_gemm2<<<dim3(MAX_TILES * (H_DIM / BN2)), 256, 0, stream>>>(aws, w2, ws_i, out);
}